// Round 5
// baseline (265.249 us; speedup 1.0000x reference)
//
#include <hip/hip_runtime.h>

// MS-G3D block. Split-GEMM path (needs ~220MB ws) with R4 fused fallback.
// N=8, C=96, T=128, V=25, WIN=3, VL=75, NS=6.

#define NB 8
#define CB 96
#define TB 128
#define VB 25
#define VLB 75
#define EPSB 1e-5f
#define XRS 104   // fallback xraw row stride (shorts)
#define TMS 104   // fallback tmp row stride
#define HBS 296   // hnb row stride (shorts)
#define BTS 104   // k1a LDS B-tile row stride (shorts): 208B rows, 2-way banks, 16B-aligned

typedef __attribute__((ext_vector_type(8))) short bf16x8;
typedef __attribute__((ext_vector_type(4))) float f32x4;

__device__ inline unsigned short f2bf(float f) {
  unsigned int u = __float_as_uint(f);
  u = (u + 0x7FFFu + ((u >> 16) & 1u)) >> 16;
  return (unsigned short)u;
}
__device__ inline float bf2f(unsigned short u) {
  return __uint_as_float(((unsigned int)u) << 16);
}

// ======================= NEW SPLIT-GEMM PATH =======================

// K0n: Wbf [ps][o][c], Bbcat [u<80][ps*80+u'<960], Wobf [o][i*3+w]; zero stats
__global__ __launch_bounds__(256) void k0n(
    const float* __restrict__ As, const float* __restrict__ Bs,
    const float* __restrict__ Ar, const float* __restrict__ Wm,
    const float* __restrict__ Wo,
    unsigned short* __restrict__ Wbf, unsigned short* __restrict__ Bb,
    unsigned short* __restrict__ Wobf, float* __restrict__ stats) {
  int i = blockIdx.x * 256 + threadIdx.x;
  if (i < 12 * 96 * 96) {
    int ps = i / 9216, rem = i % 9216, o = rem / 96, c = rem % 96;
    Wbf[i] = f2bf(Wm[o * 1152 + ps * 96 + c]);
  }
  if (i < 80 * 960) {
    int u = i / 960, k = i % 960, ps = k / 80, up = k % 80;
    float v = 0.f;
    if (u < 75 && up < 75) {
      int path = ps / 6, s = ps % 6;
      int idx = (s * 75 + u) * 75 + up;
      v = (path == 0 ? As[idx] : Bs[idx]) + Ar[idx];
    }
    Bb[i] = f2bf(v);
  }
  if (i < 96 * 288) Wobf[i] = f2bf(Wo[i]);
  if (i < 384) stats[i] = 0.f;
}

// KP: unfold x -> XUT bf16 [nt][u'<80][c<96], rows u'>=75 zeroed
__global__ __launch_bounds__(256) void kp_unfold(
    const float* __restrict__ x, unsigned short* __restrict__ XUT) {
  __shared__ float xs[96][81];
  const int tid = threadIdx.x;
  const int nt = blockIdx.x, n = nt >> 7, t = nt & 127;
  for (int idx = tid; idx < 96 * 75; idx += 256) {
    int c = idx / 75, rv = idx - c * 75;
    int w = rv / 25, v = rv % 25, tt = t - 1 + w;
    xs[c][rv] = (tt >= 0 && tt < TB) ? x[((n * CB + c) * TB + tt) * VB + v] : 0.f;
  }
  __syncthreads();
  for (int idx = tid; idx < 80 * 96; idx += 256) {
    int up = idx / 96, c = idx - up * 96;
    XUT[nt * 7680 + idx] = f2bf(up < 75 ? xs[c][up] : 0.f);
  }
}

// K1a: GEMM-A. grid = (nt/2) x 12 mt, 384 thr / 6 waves.
// TMP[nt][o][mt*80+u'] = sum_c Wbf[mt][o][c] * XUT[nt][u'][c]
__global__ __launch_bounds__(384) void k1a(
    const unsigned short* __restrict__ XUT, const unsigned short* __restrict__ Wbf,
    unsigned short* __restrict__ TMP) {
  __shared__ unsigned short bt[160 * BTS];   // [ncol<160][c], 33.3 KB
  const int tid = threadIdx.x;
  const int ntp = blockIdx.x / 12, mt = blockIdx.x % 12, nt0 = ntp * 2;
  for (int i = tid; i < 1920; i += 384) {    // copy 2 nt slabs (ushort8 units)
    bf16x8 v = *reinterpret_cast<const bf16x8*>(XUT + nt0 * 7680 + i * 8);
    int e = i * 8, row = e / 96, c8 = e - row * 96;
    *reinterpret_cast<bf16x8*>(bt + row * BTS + c8) = v;
  }
  __syncthreads();

  const int wave = tid >> 6, lane = tid & 63;
  const int l15 = lane & 15, quad = lane >> 4, q8 = quad * 8;
  const unsigned short* Ap = Wbf + mt * 9216 + (wave * 16 + l15) * 96 + q8;
  bf16x8 a[3];
#pragma unroll
  for (int kk = 0; kk < 3; ++kk) a[kk] = *reinterpret_cast<const bf16x8*>(Ap + kk * 32);

  const f32x4 zf = {0.f, 0.f, 0.f, 0.f};
  f32x4 acc[10];
#pragma unroll
  for (int nt = 0; nt < 10; ++nt) acc[nt] = zf;
#pragma unroll
  for (int nt = 0; nt < 10; ++nt)
#pragma unroll
    for (int kk = 0; kk < 3; ++kk) {
      bf16x8 b = *reinterpret_cast<const bf16x8*>(&bt[(nt * 16 + l15) * BTS + kk * 32 + q8]);
      acc[nt] = __builtin_amdgcn_mfma_f32_16x16x32_bf16(a[kk], b, acc[nt], 0, 0, 0);
    }

  const int obase = wave * 16 + quad * 4;
#pragma unroll
  for (int nt = 0; nt < 10; ++nt) {
    int ncol = nt * 16 + l15;
    int d = (ncol >= 80) ? 1 : 0;
    int up = ncol - d * 80;
    unsigned short* dst = TMP + (nt0 + d) * 92160 + mt * 80 + up;
#pragma unroll
    for (int r = 0; r < 4; ++r)
      dst[(obase + r) * 960] = f2bf(acc[nt][r]);   // pads get exact 0 (zeroed B rows)
  }
}

// K1b: GEMM-B. grid = 512 (2 nt each), 384 thr / 6 waves. Zero LDS staging.
// h[o,u] = sum_k TMP[nt][o][k] * Bb[u][k]; epilogue bias+relu+BN1 stats+h_relu bf16
__global__ __launch_bounds__(384) void k1b(
    const unsigned short* __restrict__ TMP, const unsigned short* __restrict__ Bb,
    const float* __restrict__ bm, unsigned short* __restrict__ h_relu,
    float* __restrict__ stats1) {
  __shared__ float st1s[96], st2s[96];
  const int tid = threadIdx.x;
  const int nt0 = blockIdx.x * 2;
  const int wave = tid >> 6, lane = tid & 63;
  const int l15 = lane & 15, quad = lane >> 4, q8 = quad * 8;
  const unsigned short* Ap0 = TMP + nt0 * 92160 + (wave * 16 + l15) * 960 + q8;
  const unsigned short* Ap1 = Ap0 + 92160;
  const unsigned short* Bp = Bb + l15 * 960 + q8;

  const f32x4 zf = {0.f, 0.f, 0.f, 0.f};
  f32x4 acc[2][5];
#pragma unroll
  for (int d = 0; d < 2; ++d)
#pragma unroll
    for (int nt = 0; nt < 5; ++nt) acc[d][nt] = zf;

#pragma unroll 3
  for (int kk = 0; kk < 30; ++kk) {
    bf16x8 a0 = *reinterpret_cast<const bf16x8*>(Ap0 + kk * 32);
    bf16x8 a1 = *reinterpret_cast<const bf16x8*>(Ap1 + kk * 32);
#pragma unroll
    for (int nt = 0; nt < 5; ++nt) {
      bf16x8 b = *reinterpret_cast<const bf16x8*>(Bp + nt * 15360 + kk * 32);
      acc[0][nt] = __builtin_amdgcn_mfma_f32_16x16x32_bf16(a0, b, acc[0][nt], 0, 0, 0);
      acc[1][nt] = __builtin_amdgcn_mfma_f32_16x16x32_bf16(a1, b, acc[1][nt], 0, 0, 0);
    }
  }

  const int orow = wave * 16 + quad * 4;
  float s1[4] = {0.f, 0.f, 0.f, 0.f}, s2[4] = {0.f, 0.f, 0.f, 0.f};
#pragma unroll
  for (int d = 0; d < 2; ++d) {
    const int ntg = nt0 + d, n = ntg >> 7, t = ntg & 127;
#pragma unroll
    for (int r = 0; r < 4; ++r) {
      const int o = orow + r;
      const float bias = bm[o];
      unsigned short* hp = h_relu + ((n * CB + o) * TB + t) * VLB;
#pragma unroll
      for (int nt = 0; nt < 5; ++nt) {
        int u = nt * 16 + l15;
        if (u < VLB) {
          float v = acc[d][nt][r] + bias;
          v = v > 0.f ? v : 0.f;
          hp[u] = f2bf(v);
          s1[r] += v;
          s2[r] += v * v;
        }
      }
    }
  }
#pragma unroll
  for (int off = 1; off < 16; off <<= 1) {
#pragma unroll
    for (int r = 0; r < 4; ++r) {
      s1[r] += __shfl_xor(s1[r], off, 64);
      s2[r] += __shfl_xor(s2[r], off, 64);
    }
  }
  if (l15 == 0) {
#pragma unroll
    for (int r = 0; r < 4; ++r) { st1s[orow + r] = s1[r]; st2s[orow + r] = s2[r]; }
  }
  __syncthreads();
  if (tid < 96) {
    atomicAdd(&stats1[tid], st1s[tid]);
    atomicAdd(&stats1[96 + tid], st2s[tid]);
  }
}

// K3n: BN1-finalize + relu + out_conv (MFMA, 2 t/blk), bf16 h_relu input
__global__ __launch_bounds__(384) void k3n(
    const unsigned short* __restrict__ h_relu, const float* __restrict__ stats1,
    const float* __restrict__ g1, const float* __restrict__ bt1,
    const unsigned short* __restrict__ Wobf, const float* __restrict__ bo,
    float* __restrict__ out_pre, float* __restrict__ stats2) {
  __shared__ unsigned short hnb[2][32 * HBS];
  __shared__ float a1s[96], b1s[96];
  __shared__ float st1[96], st2[96];
  const int tid = threadIdx.x;
  const int n = blockIdx.x >> 6, t0 = (blockIdx.x & 63) * 2;

  if (tid < 96) {
    const float inv = 1.f / (8.f * 128.f * 75.f);
    float m = stats1[tid] * inv;
    float var = stats1[96 + tid] * inv - m * m;
    float a = g1[tid] * rsqrtf(var + EPSB);
    a1s[tid] = a;
    b1s[tid] = bt1[tid] - m * a;
  }
  for (int idx = tid; idx < 2 * 7 * HBS; idx += 384) {
    int d = idx / (7 * HBS), rm = idx % (7 * HBS);
    hnb[d][25 * HBS + rm] = 0;
  }
  __syncthreads();

  for (int idx = tid; idx < 2 * 96 * 75; idx += 384) {
    int d = idx / 7200, rm = idx % 7200;
    int i = rm / 75, u = rm - i * 75;
    float hv = bf2f(h_relu[((n * CB + i) * TB + t0 + d) * VLB + u]);
    float v = a1s[i] * hv + b1s[i];
    v = v > 0.f ? v : 0.f;
    int w = u / 25, vv = u - w * 25;
    hnb[d][vv * HBS + i * 3 + w] = f2bf(v);
  }
  __syncthreads();

  const int wave = tid >> 6, lane = tid & 63;
  const int l15 = lane & 15, quad = lane >> 4, q8 = quad * 8;
  const f32x4 zf = {0.f, 0.f, 0.f, 0.f};
  f32x4 acc[2][2] = {{zf, zf}, {zf, zf}};
  const unsigned short* Apw = Wobf + (wave * 16 + l15) * 288 + q8;
#pragma unroll
  for (int kk = 0; kk < 9; ++kk) {
    bf16x8 a = *reinterpret_cast<const bf16x8*>(Apw + kk * 32);
#pragma unroll
    for (int d = 0; d < 2; ++d) {
      bf16x8 b0 = *reinterpret_cast<const bf16x8*>(&hnb[d][l15 * HBS + kk * 32 + q8]);
      bf16x8 b1 = *reinterpret_cast<const bf16x8*>(&hnb[d][(16 + l15) * HBS + kk * 32 + q8]);
      acc[d][0] = __builtin_amdgcn_mfma_f32_16x16x32_bf16(a, b0, acc[d][0], 0, 0, 0);
      acc[d][1] = __builtin_amdgcn_mfma_f32_16x16x32_bf16(a, b1, acc[d][1], 0, 0, 0);
    }
  }

  const int orow = wave * 16 + quad * 4;
  float s1[4] = {0.f, 0.f, 0.f, 0.f}, s2[4] = {0.f, 0.f, 0.f, 0.f};
#pragma unroll
  for (int d = 0; d < 2; ++d) {
#pragma unroll
    for (int nt = 0; nt < 2; ++nt) {
      int v = nt * 16 + l15;
      if (v < VB) {
#pragma unroll
        for (int r = 0; r < 4; ++r) {
          const int o = orow + r;
          float val = acc[d][nt][r] + bo[o];
          out_pre[((n * CB + o) * TB + t0 + d) * VB + v] = val;
          s1[r] += val;
          s2[r] += val * val;
        }
      }
    }
  }
#pragma unroll
  for (int off = 1; off < 16; off <<= 1) {
#pragma unroll
    for (int r = 0; r < 4; ++r) {
      s1[r] += __shfl_xor(s1[r], off, 64);
      s2[r] += __shfl_xor(s2[r], off, 64);
    }
  }
  if (l15 == 0) {
#pragma unroll
    for (int r = 0; r < 4; ++r) { st1[orow + r] = s1[r]; st2[orow + r] = s2[r]; }
  }
  __syncthreads();
  if (tid < 96) {
    atomicAdd(&stats2[tid], st1[tid]);
    atomicAdd(&stats2[96 + tid], st2[tid]);
  }
}

// K5: BN2 finalize (float4)
__global__ __launch_bounds__(256) void k5_bn2(
    const float* __restrict__ out_pre, const float* __restrict__ stats2,
    const float* __restrict__ g2, const float* __restrict__ bt2,
    float* __restrict__ out) {
  int idx = blockIdx.x * 256 + threadIdx.x;
  if (idx >= NB * CB * TB * VB / 4) return;
  int o = (idx / (TB * VB / 4)) % CB;
  const float inv = 1.f / (8.f * 128.f * 25.f);
  float m = stats2[o] * inv;
  float var = stats2[96 + o] * inv - m * m;
  float a = g2[o] * rsqrtf(var + EPSB);
  float b = bt2[o] - m * a;
  f32x4 vin = reinterpret_cast<const f32x4*>(out_pre)[idx];
  f32x4 vo;
#pragma unroll
  for (int j = 0; j < 4; ++j) vo[j] = a * vin[j] + b;
  reinterpret_cast<f32x4*>(out)[idx] = vo;
}

// ======================= FALLBACK (R4, verbatim) =======================

__global__ __launch_bounds__(256) void k0f(
    const float* __restrict__ As, const float* __restrict__ Bs,
    const float* __restrict__ Ar, const float* __restrict__ Wm,
    const float* __restrict__ Wo,
    unsigned short* __restrict__ ABbf, unsigned short* __restrict__ Wbf,
    unsigned short* __restrict__ Wobf, float* __restrict__ stats) {
  int i = blockIdx.x * 256 + threadIdx.x;
  if (i < 12 * 96 * 96) {
    int ps = i / 9216, rem = i % 9216, o = rem / 96, c = rem % 96;
    Wbf[i] = f2bf(Wm[o * 1152 + ps * 96 + c]);
  }
  if (i < 12 * 80 * 96) {
    int ps = i / 7680, rem = i % 7680, u = rem / 96, up = rem % 96;
    float v = 0.f;
    if (u < 75 && up < 75) {
      int path = ps / 6, s = ps % 6;
      int idx = (s * 75 + u) * 75 + up;
      v = (path == 0 ? As[idx] : Bs[idx]) + Ar[idx];
    }
    ABbf[i] = f2bf(v);
  }
  if (i < 96 * 288) Wobf[i] = f2bf(Wo[i]);
  if (i < 384) stats[i] = 0.f;
}

__global__ __launch_bounds__(384, 3) void k1_fb(
    const float* __restrict__ x, const unsigned short* __restrict__ ABbf,
    const unsigned short* __restrict__ Wbf, const float* __restrict__ bm,
    float* __restrict__ h_relu, float* __restrict__ stats1) {
  __shared__ unsigned short xraw[80 * XRS];
  __shared__ unsigned short tmp_s[96 * TMS];
  __shared__ float st1s[96], st2s[96];
  const int tid = threadIdx.x;
  const int n = blockIdx.x >> 7, t = blockIdx.x & 127;
  const int wave = tid >> 6, lane = tid & 63;
  const int l15 = lane & 15, quad = lane >> 4, q8 = quad * 8;
  const int wrow16 = wave * 16;

  for (int idx = tid; idx < 96 * 80; idx += 384) {
    int c = idx / 80, r = idx - c * 80;
    float v = 0.f;
    if (r < 75) {
      int tt = t - 1 + r / 25, vv = r % 25;
      if (tt >= 0 && tt < TB) v = x[((n * CB + c) * TB + tt) * VB + vv];
    }
    xraw[r * XRS + c] = f2bf(v);
  }
  {
    int row = wrow16 + l15;
    int c0 = 80 + quad * 4;
#pragma unroll
    for (int j = 0; j < 4; ++j) tmp_s[row * TMS + c0 + j] = 0;
  }
  __syncthreads();

  const f32x4 zf = {0.f, 0.f, 0.f, 0.f};
  f32x4 acc2[5], acc1[5], acc1n[5];
#pragma unroll
  for (int nt = 0; nt < 5; ++nt) acc2[nt] = zf;
  const unsigned short* Wrow = Wbf + (wrow16 + l15) * 96 + q8;
#pragma unroll
  for (int nt = 0; nt < 5; ++nt) acc1[nt] = zf;
#pragma unroll
  for (int kk = 0; kk < 3; ++kk) {
    bf16x8 a = *reinterpret_cast<const bf16x8*>(Wrow + kk * 32);
#pragma unroll
    for (int nt = 0; nt < 5; ++nt) {
      bf16x8 b = *reinterpret_cast<const bf16x8*>(&xraw[(nt * 16 + l15) * XRS + kk * 32 + q8]);
      acc1[nt] = __builtin_amdgcn_mfma_f32_16x16x32_bf16(a, b, acc1[nt], 0, 0, 0);
    }
  }
  for (int ps = 0; ps < 12; ++ps) {
#pragma unroll
    for (int nt = 0; nt < 5; ++nt) {
      int col = nt * 16 + l15;
#pragma unroll
      for (int r = 0; r < 4; ++r) {
        unsigned short v = (col < 75) ? f2bf(acc1[nt][r]) : (unsigned short)0;
        tmp_s[(wrow16 + quad * 4 + r) * TMS + col] = v;
      }
    }
    const unsigned short* Bp = ABbf + ps * 7680 + l15 * 96 + q8;
    bf16x8 bcur[5], bnxt[5];
#pragma unroll
    for (int nt = 0; nt < 5; ++nt)
      bcur[nt] = *reinterpret_cast<const bf16x8*>(Bp + nt * 1536);
#pragma unroll
    for (int nt = 0; nt < 5; ++nt) acc1n[nt] = zf;
    if (ps < 11) {
      const unsigned short* Wp = Wrow + (ps + 1) * 9216;
#pragma unroll
      for (int kk = 0; kk < 3; ++kk) {
        bf16x8 a = *reinterpret_cast<const bf16x8*>(Wp + kk * 32);
#pragma unroll
        for (int nt = 0; nt < 5; ++nt) {
          bf16x8 b = *reinterpret_cast<const bf16x8*>(&xraw[(nt * 16 + l15) * XRS + kk * 32 + q8]);
          acc1n[nt] = __builtin_amdgcn_mfma_f32_16x16x32_bf16(a, b, acc1n[nt], 0, 0, 0);
        }
      }
    }
#pragma unroll
    for (int kk = 0; kk < 3; ++kk) {
      if (kk < 2) {
#pragma unroll
        for (int nt = 0; nt < 5; ++nt)
          bnxt[nt] = *reinterpret_cast<const bf16x8*>(Bp + nt * 1536 + (kk + 1) * 32);
      }
      bf16x8 a2 = *reinterpret_cast<const bf16x8*>(&tmp_s[(wrow16 + l15) * TMS + kk * 32 + q8]);
#pragma unroll
      for (int nt = 0; nt < 5; ++nt)
        acc2[nt] = __builtin_amdgcn_mfma_f32_16x16x32_bf16(a2, bcur[nt], acc2[nt], 0, 0, 0);
      if (kk < 2) {
#pragma unroll
        for (int nt = 0; nt < 5; ++nt) bcur[nt] = bnxt[nt];
      }
    }
#pragma unroll
    for (int nt = 0; nt < 5; ++nt) acc1[nt] = acc1n[nt];
  }
  const int orow = wrow16 + quad * 4;
  float s1[4] = {0.f, 0.f, 0.f, 0.f}, s2[4] = {0.f, 0.f, 0.f, 0.f};
#pragma unroll
  for (int r = 0; r < 4; ++r) {
    const int o = orow + r;
    const float bias = bm[o];
    float* hp = h_relu + ((n * CB + o) * TB + t) * VLB;
#pragma unroll
    for (int nt = 0; nt < 5; ++nt) {
      int u = nt * 16 + l15;
      if (u < VLB) {
        float v = acc2[nt][r] + bias;
        v = v > 0.f ? v : 0.f;
        hp[u] = v;
        s1[r] += v;
        s2[r] += v * v;
      }
    }
  }
#pragma unroll
  for (int off = 1; off < 16; off <<= 1) {
#pragma unroll
    for (int r = 0; r < 4; ++r) {
      s1[r] += __shfl_xor(s1[r], off, 64);
      s2[r] += __shfl_xor(s2[r], off, 64);
    }
  }
  if (l15 == 0) {
#pragma unroll
    for (int r = 0; r < 4; ++r) { st1s[orow + r] = s1[r]; st2s[orow + r] = s2[r]; }
  }
  __syncthreads();
  if (tid < 96) {
    atomicAdd(&stats1[tid], st1s[tid]);
    atomicAdd(&stats1[96 + tid], st2s[tid]);
  }
}

__global__ __launch_bounds__(384) void k3_fb(
    const float* __restrict__ h_relu, const float* __restrict__ stats1,
    const float* __restrict__ g1, const float* __restrict__ bt1,
    const unsigned short* __restrict__ Wobf, const float* __restrict__ bo,
    float* __restrict__ out_pre, float* __restrict__ stats2) {
  __shared__ unsigned short hnb[2][32 * HBS];
  __shared__ float a1s[96], b1s[96];
  __shared__ float st1[96], st2[96];
  const int tid = threadIdx.x;
  const int n = blockIdx.x >> 6, t0 = (blockIdx.x & 63) * 2;
  if (tid < 96) {
    const float inv = 1.f / (8.f * 128.f * 75.f);
    float m = stats1[tid] * inv;
    float var = stats1[96 + tid] * inv - m * m;
    float a = g1[tid] * rsqrtf(var + EPSB);
    a1s[tid] = a;
    b1s[tid] = bt1[tid] - m * a;
  }
  for (int idx = tid; idx < 2 * 7 * HBS; idx += 384) {
    int d = idx / (7 * HBS), rm = idx % (7 * HBS);
    hnb[d][25 * HBS + rm] = 0;
  }
  __syncthreads();
  for (int idx = tid; idx < 2 * 96 * 75; idx += 384) {
    int d = idx / 7200, rm = idx % 7200;
    int i = rm / 75, u = rm - i * 75;
    float hv = h_relu[((n * CB + i) * TB + t0 + d) * VLB + u];
    float v = a1s[i] * hv + b1s[i];
    v = v > 0.f ? v : 0.f;
    int w = u / 25, vv = u - w * 25;
    hnb[d][vv * HBS + i * 3 + w] = f2bf(v);
  }
  __syncthreads();
  const int wave = tid >> 6, lane = tid & 63;
  const int l15 = lane & 15, quad = lane >> 4, q8 = quad * 8;
  const f32x4 zf = {0.f, 0.f, 0.f, 0.f};
  f32x4 acc[2][2] = {{zf, zf}, {zf, zf}};
  const unsigned short* Apw = Wobf + (wave * 16 + l15) * 288 + q8;
#pragma unroll
  for (int kk = 0; kk < 9; ++kk) {
    bf16x8 a = *reinterpret_cast<const bf16x8*>(Apw + kk * 32);
#pragma unroll
    for (int d = 0; d < 2; ++d) {
      bf16x8 b0 = *reinterpret_cast<const bf16x8*>(&hnb[d][l15 * HBS + kk * 32 + q8]);
      bf16x8 b1 = *reinterpret_cast<const bf16x8*>(&hnb[d][(16 + l15) * HBS + kk * 32 + q8]);
      acc[d][0] = __builtin_amdgcn_mfma_f32_16x16x32_bf16(a, b0, acc[d][0], 0, 0, 0);
      acc[d][1] = __builtin_amdgcn_mfma_f32_16x16x32_bf16(a, b1, acc[d][1], 0, 0, 0);
    }
  }
  const int orow = wave * 16 + quad * 4;
  float s1[4] = {0.f, 0.f, 0.f, 0.f}, s2[4] = {0.f, 0.f, 0.f, 0.f};
#pragma unroll
  for (int d = 0; d < 2; ++d) {
#pragma unroll
    for (int nt = 0; nt < 2; ++nt) {
      int v = nt * 16 + l15;
      if (v < VB) {
#pragma unroll
        for (int r = 0; r < 4; ++r) {
          const int o = orow + r;
          float val = acc[d][nt][r] + bo[o];
          out_pre[((n * CB + o) * TB + t0 + d) * VB + v] = val;
          s1[r] += val;
          s2[r] += val * val;
        }
      }
    }
  }
#pragma unroll
  for (int off = 1; off < 16; off <<= 1) {
#pragma unroll
    for (int r = 0; r < 4; ++r) {
      s1[r] += __shfl_xor(s1[r], off, 64);
      s2[r] += __shfl_xor(s2[r], off, 64);
    }
  }
  if (l15 == 0) {
#pragma unroll
    for (int r = 0; r < 4; ++r) { st1[orow + r] = s1[r]; st2[orow + r] = s2[r]; }
  }
  __syncthreads();
  if (tid < 96) {
    atomicAdd(&stats2[tid], st1[tid]);
    atomicAdd(&stats2[96 + tid], st2[tid]);
  }
}

// ======================= HOST =======================

extern "C" void kernel_launch(void* const* d_in, const int* in_sizes, int n_in,
                              void* d_out, int out_size, void* d_ws, size_t ws_size,
                              hipStream_t stream) {
  const float* x   = (const float*)d_in[0];
  const float* As  = (const float*)d_in[1];
  const float* Bs  = (const float*)d_in[2];
  const float* Ar  = (const float*)d_in[3];
  const float* Wm  = (const float*)d_in[4];
  const float* bm  = (const float*)d_in[5];
  const float* g1  = (const float*)d_in[6];
  const float* bt1 = (const float*)d_in[7];
  const float* Wo  = (const float*)d_in[8];
  const float* bo  = (const float*)d_in[9];
  const float* g2  = (const float*)d_in[10];
  const float* bt2 = (const float*)d_in[11];
  float* out = (float*)d_out;

  const size_t NEED_NEW = 219649536ull;  // bytes for split-GEMM path

  if (ws_size >= NEED_NEW) {
    unsigned short* us = (unsigned short*)d_ws;
    unsigned short* XUT  = us;                      // 7,864,320
    unsigned short* TMP  = us + 7864320;            // 94,371,840
    unsigned short* HR   = us + 102236160;          // 7,372,800
    unsigned short* Wbf  = us + 109608960;          // 110,592
    unsigned short* Bb   = us + 109719552;          // 76,800
    unsigned short* Wobf = us + 109796352;          // 27,648
    float* stats = (float*)(us + 109824000);        // 384
    float* stats1 = stats, *stats2 = stats + 192;
    float* out_pre = (float*)d_ws;                  // aliases XUT region (dead by k3n)

    k0n<<<432, 256, 0, stream>>>(As, Bs, Ar, Wm, Wo, Wbf, Bb, Wobf, stats);
    kp_unfold<<<1024, 256, 0, stream>>>(x, XUT);
    k1a<<<6144, 384, 0, stream>>>(XUT, Wbf, TMP);
    k1b<<<512, 384, 0, stream>>>(TMP, Bb, bm, HR, stats1);
    k3n<<<512, 384, 0, stream>>>(HR, stats1, g1, bt1, Wobf, bo, out_pre, stats2);
    k5_bn2<<<(NB * CB * TB * VB / 4 + 255) / 256, 256, 0, stream>>>(out_pre, stats2, g2, bt2, out);
  } else {
    float* ws      = (float*)d_ws;
    float* h_relu  = ws;
    float* out_pre = ws + 7372800;
    unsigned short* ABbf = (unsigned short*)(ws + 9830400);
    unsigned short* Wbf  = ABbf + 92160;
    unsigned short* Wobf = Wbf + 110592;
    float* stats   = (float*)(Wobf + 27648);
    float* stats1  = stats, *stats2 = stats + 192;

    k0f<<<432, 256, 0, stream>>>(As, Bs, Ar, Wm, Wo, ABbf, Wbf, Wobf, stats);
    k1_fb<<<NB * TB, 384, 0, stream>>>(x, ABbf, Wbf, bm, h_relu, stats1);
    k3_fb<<<NB * TB / 2, 384, 0, stream>>>(h_relu, stats1, g1, bt1, Wobf, bo, out_pre, stats2);
    k5_bn2<<<(NB * CB * TB * VB / 4 + 255) / 256, 256, 0, stream>>>(out_pre, stats2, g2, bt2, out);
  }
}

// Round 6
// 247.376 us; speedup vs baseline: 1.0722x; 1.0722x over previous
//
#include <hip/hip_runtime.h>

// MS-G3D block. Fused bf16-MFMA k1: t-chunk=2 + software pipeline, zero barriers
// in ps loop. N=8, C=96, T=128, V=25, WIN=3, VL=75, NS=6.

#define NB 8
#define CB 96
#define TB 128
#define VB 25
#define VLB 75
#define EPSB 1e-5f
#define XRS 104   // xraw row stride (shorts): 208B rows, 16B-aligned, 2-way banks
#define TMS 104   // tmp row stride
#define HBS 296   // hnb row stride (shorts)

typedef __attribute__((ext_vector_type(8))) short bf16x8;
typedef __attribute__((ext_vector_type(4))) float f32x4;

__device__ inline unsigned short f2bf(float f) {
  unsigned int u = __float_as_uint(f);
  u = (u + 0x7FFFu + ((u >> 16) & 1u)) >> 16;
  return (unsigned short)u;
}
__device__ inline float bf2f(unsigned short u) {
  return __uint_as_float(((unsigned int)u) << 16);
}

// ---------------- K0: pre-cast W, AB, Wo to bf16; zero stats ----------------
__global__ __launch_bounds__(256) void k0_init(
    const float* __restrict__ As, const float* __restrict__ Bs,
    const float* __restrict__ Ar, const float* __restrict__ Wm,
    const float* __restrict__ Wo,
    unsigned short* __restrict__ ABbf, unsigned short* __restrict__ Wbf,
    unsigned short* __restrict__ Wobf, float* __restrict__ stats) {
  int i = blockIdx.x * 256 + threadIdx.x;
  if (i < 12 * 96 * 96) {                       // Wbf[ps][o][c]
    int ps = i / 9216, rem = i % 9216, o = rem / 96, c = rem % 96;
    Wbf[i] = f2bf(Wm[o * 1152 + ps * 96 + c]);
  }
  if (i < 12 * 80 * 96) {                       // ABbf[ps][u][u'] n-major k-contig
    int ps = i / 7680, rem = i % 7680, u = rem / 96, up = rem % 96;
    float v = 0.f;
    if (u < 75 && up < 75) {
      int path = ps / 6, s = ps % 6;
      int idx = (s * 75 + u) * 75 + up;
      v = (path == 0 ? As[idx] : Bs[idx]) + Ar[idx];
    }
    ABbf[i] = f2bf(v);
  }
  if (i < 96 * 288) Wobf[i] = f2bf(Wo[i]);      // (o,i,w) flat == [o][i*3+w]
  if (i < 384) stats[i] = 0.f;
}

// ---------------- K1: t2 + pipelined (MLP -> agg) x12 MFMA ------------------
// grid = N*T/2 = 512 blocks (2/CU, all resident), 384 threads (6 waves).
// Wave w owns o-rows [16w,16w+16). Order per ps:
//   G1(dt0) -> wr tmp0 -> G1(dt1) [covers tmp0 lat] -> wr tmp1
//   -> GEMM2 kk-loop interleaved dt0/dt1 [a2_0+5 MFMA cover a2_1] w/ b2 prefetch.
__global__ __launch_bounds__(384, 3) void k1t2(
    const float* __restrict__ x, const unsigned short* __restrict__ ABbf,
    const unsigned short* __restrict__ Wbf, const float* __restrict__ bm,
    unsigned short* __restrict__ h_relu, float* __restrict__ stats1) {
  __shared__ unsigned short xraw[112 * XRS];     // rows r=tt_rel*25+v, 100..111 zero
  __shared__ unsigned short tmp_s[2][96 * TMS];  // per-dt tmp [o][u']
  __shared__ float st1s[96], st2s[96];
  const int tid = threadIdx.x;
  const int n = blockIdx.x >> 6, t0 = (blockIdx.x & 63) * 2;
  const int wave = tid >> 6, lane = tid & 63;
  const int l15 = lane & 15, quad = lane >> 4, q8 = quad * 8;
  const int wrow16 = wave * 16;

  // stage raw x slice: tt = t0-1 .. t0+2 (100 rows), zero-pad rows to 112
  for (int idx = tid; idx < 96 * 112; idx += 384) {
    int c = idx / 112, r = idx - c * 112;
    float v = 0.f;
    if (r < 100) {
      int tt = t0 - 1 + r / 25, vv = r % 25;
      if (tt >= 0 && tt < TB) v = x[((n * CB + c) * TB + tt) * VB + vv];
    }
    xraw[r * XRS + c] = f2bf(v);
  }
  // zero tmp K-pad cols [80,96) for both buffers (cols 75..79 written 0 each ps)
  for (int idx = tid; idx < 2 * 96 * 16; idx += 384) {
    int b = idx / (96 * 16), rem = idx - b * 96 * 16;
    tmp_s[b][(rem / 16) * TMS + 80 + rem % 16] = 0;
  }
  __syncthreads();

  const f32x4 zf = {0.f, 0.f, 0.f, 0.f};
  f32x4 acc2[2][5];
#pragma unroll
  for (int d = 0; d < 2; ++d)
#pragma unroll
    for (int nt = 0; nt < 5; ++nt) acc2[d][nt] = zf;

  const unsigned short* Wrow = Wbf + (wrow16 + l15) * 96 + q8;

  for (int ps = 0; ps < 12; ++ps) {
    const unsigned short* Wp = Wrow + ps * 9216;
    bf16x8 wa[3];
#pragma unroll
    for (int kk = 0; kk < 3; ++kk) wa[kk] = *reinterpret_cast<const bf16x8*>(Wp + kk * 32);

    // GEMM1 dt=0
    f32x4 acc1[5];
#pragma unroll
    for (int nt = 0; nt < 5; ++nt) acc1[nt] = zf;
#pragma unroll
    for (int kk = 0; kk < 3; ++kk)
#pragma unroll
      for (int nt = 0; nt < 5; ++nt) {
        bf16x8 b = *reinterpret_cast<const bf16x8*>(&xraw[(nt * 16 + l15) * XRS + kk * 32 + q8]);
        acc1[nt] = __builtin_amdgcn_mfma_f32_16x16x32_bf16(wa[kk], b, acc1[nt], 0, 0, 0);
      }
    // write tmp0 (cols >=75 -> 0)
#pragma unroll
    for (int nt = 0; nt < 5; ++nt) {
      int col = nt * 16 + l15;
#pragma unroll
      for (int r = 0; r < 4; ++r) {
        unsigned short v = (col < 75) ? f2bf(acc1[nt][r]) : (unsigned short)0;
        tmp_s[0][(wrow16 + quad * 4 + r) * TMS + col] = v;
      }
    }
    // GEMM1 dt=1 (independent MFMA work covers tmp0 write->read latency)
#pragma unroll
    for (int nt = 0; nt < 5; ++nt) acc1[nt] = zf;
#pragma unroll
    for (int kk = 0; kk < 3; ++kk)
#pragma unroll
      for (int nt = 0; nt < 5; ++nt) {
        bf16x8 b = *reinterpret_cast<const bf16x8*>(&xraw[(25 + nt * 16 + l15) * XRS + kk * 32 + q8]);
        acc1[nt] = __builtin_amdgcn_mfma_f32_16x16x32_bf16(wa[kk], b, acc1[nt], 0, 0, 0);
      }
    // write tmp1
#pragma unroll
    for (int nt = 0; nt < 5; ++nt) {
      int col = nt * 16 + l15;
#pragma unroll
      for (int r = 0; r < 4; ++r) {
        unsigned short v = (col < 75) ? f2bf(acc1[nt][r]) : (unsigned short)0;
        tmp_s[1][(wrow16 + quad * 4 + r) * TMS + col] = v;
      }
    }

    // GEMM2 both dt, kk-interleaved, b2 frags shared across dt + 2-stage prefetch
    const unsigned short* Bp = ABbf + ps * 7680 + l15 * 96 + q8;
    bf16x8 bcur[5], bnxt[5];
#pragma unroll
    for (int nt = 0; nt < 5; ++nt)
      bcur[nt] = *reinterpret_cast<const bf16x8*>(Bp + nt * 1536);
#pragma unroll
    for (int kk = 0; kk < 3; ++kk) {
      if (kk < 2) {
#pragma unroll
        for (int nt = 0; nt < 5; ++nt)
          bnxt[nt] = *reinterpret_cast<const bf16x8*>(Bp + nt * 1536 + (kk + 1) * 32);
      }
      bf16x8 a0 = *reinterpret_cast<const bf16x8*>(&tmp_s[0][(wrow16 + l15) * TMS + kk * 32 + q8]);
#pragma unroll
      for (int nt = 0; nt < 5; ++nt)
        acc2[0][nt] = __builtin_amdgcn_mfma_f32_16x16x32_bf16(a0, bcur[nt], acc2[0][nt], 0, 0, 0);
      bf16x8 a1 = *reinterpret_cast<const bf16x8*>(&tmp_s[1][(wrow16 + l15) * TMS + kk * 32 + q8]);
#pragma unroll
      for (int nt = 0; nt < 5; ++nt)
        acc2[1][nt] = __builtin_amdgcn_mfma_f32_16x16x32_bf16(a1, bcur[nt], acc2[1][nt], 0, 0, 0);
      if (kk < 2) {
#pragma unroll
        for (int nt = 0; nt < 5; ++nt) bcur[nt] = bnxt[nt];
      }
    }
  }

  // epilogue: bias + relu + bf16 store + BN1 partial stats (both dt)
  const int orow = wrow16 + quad * 4;
  float s1[4] = {0.f, 0.f, 0.f, 0.f}, s2[4] = {0.f, 0.f, 0.f, 0.f};
#pragma unroll
  for (int d = 0; d < 2; ++d) {
    const int t = t0 + d;
#pragma unroll
    for (int r = 0; r < 4; ++r) {
      const int o = orow + r;
      const float bias = bm[o];
      unsigned short* hp = h_relu + ((n * CB + o) * TB + t) * VLB;
#pragma unroll
      for (int nt = 0; nt < 5; ++nt) {
        int u = nt * 16 + l15;
        if (u < VLB) {
          float v = acc2[d][nt][r] + bias;
          v = v > 0.f ? v : 0.f;
          hp[u] = f2bf(v);
          s1[r] += v;
          s2[r] += v * v;
        }
      }
    }
  }
#pragma unroll
  for (int off = 1; off < 16; off <<= 1) {
#pragma unroll
    for (int r = 0; r < 4; ++r) {
      s1[r] += __shfl_xor(s1[r], off, 64);
      s2[r] += __shfl_xor(s2[r], off, 64);
    }
  }
  if (l15 == 0) {
#pragma unroll
    for (int r = 0; r < 4; ++r) { st1s[orow + r] = s1[r]; st2s[orow + r] = s2[r]; }
  }
  __syncthreads();
  if (tid < 96) {
    atomicAdd(&stats1[tid], st1s[tid]);
    atomicAdd(&stats1[96 + tid], st2s[tid]);
  }
}

// ---------------- K3: BN1-finalize + relu + out_conv (MFMA, 2 t/blk) --------
__global__ __launch_bounds__(384) void k3n(
    const unsigned short* __restrict__ h_relu, const float* __restrict__ stats1,
    const float* __restrict__ g1, const float* __restrict__ bt1,
    const unsigned short* __restrict__ Wobf, const float* __restrict__ bo,
    float* __restrict__ out_pre, float* __restrict__ stats2) {
  __shared__ unsigned short hnb[2][32 * HBS];
  __shared__ float a1s[96], b1s[96];
  __shared__ float st1[96], st2[96];
  const int tid = threadIdx.x;
  const int n = blockIdx.x >> 6, t0 = (blockIdx.x & 63) * 2;

  if (tid < 96) {
    const float inv = 1.f / (8.f * 128.f * 75.f);
    float m = stats1[tid] * inv;
    float var = stats1[96 + tid] * inv - m * m;
    float a = g1[tid] * rsqrtf(var + EPSB);
    a1s[tid] = a;
    b1s[tid] = bt1[tid] - m * a;
  }
  for (int idx = tid; idx < 2 * 7 * HBS; idx += 384) {
    int d = idx / (7 * HBS), rm = idx % (7 * HBS);
    hnb[d][25 * HBS + rm] = 0;
  }
  __syncthreads();

  for (int idx = tid; idx < 2 * 96 * 75; idx += 384) {
    int d = idx / 7200, rm = idx % 7200;
    int i = rm / 75, u = rm - i * 75;
    float hv = bf2f(h_relu[((n * CB + i) * TB + t0 + d) * VLB + u]);
    float v = a1s[i] * hv + b1s[i];
    v = v > 0.f ? v : 0.f;
    int w = u / 25, vv = u - w * 25;
    hnb[d][vv * HBS + i * 3 + w] = f2bf(v);
  }
  __syncthreads();

  const int wave = tid >> 6, lane = tid & 63;
  const int l15 = lane & 15, quad = lane >> 4, q8 = quad * 8;
  const f32x4 zf = {0.f, 0.f, 0.f, 0.f};
  f32x4 acc[2][2] = {{zf, zf}, {zf, zf}};
  const unsigned short* Apw = Wobf + (wave * 16 + l15) * 288 + q8;
#pragma unroll
  for (int kk = 0; kk < 9; ++kk) {
    bf16x8 a = *reinterpret_cast<const bf16x8*>(Apw + kk * 32);
#pragma unroll
    for (int d = 0; d < 2; ++d) {
      bf16x8 b0 = *reinterpret_cast<const bf16x8*>(&hnb[d][l15 * HBS + kk * 32 + q8]);
      bf16x8 b1 = *reinterpret_cast<const bf16x8*>(&hnb[d][(16 + l15) * HBS + kk * 32 + q8]);
      acc[d][0] = __builtin_amdgcn_mfma_f32_16x16x32_bf16(a, b0, acc[d][0], 0, 0, 0);
      acc[d][1] = __builtin_amdgcn_mfma_f32_16x16x32_bf16(a, b1, acc[d][1], 0, 0, 0);
    }
  }

  const int orow = wave * 16 + quad * 4;
  float s1[4] = {0.f, 0.f, 0.f, 0.f}, s2[4] = {0.f, 0.f, 0.f, 0.f};
#pragma unroll
  for (int d = 0; d < 2; ++d) {
#pragma unroll
    for (int nt = 0; nt < 2; ++nt) {
      int v = nt * 16 + l15;
      if (v < VB) {
#pragma unroll
        for (int r = 0; r < 4; ++r) {
          const int o = orow + r;
          float val = acc[d][nt][r] + bo[o];
          out_pre[((n * CB + o) * TB + t0 + d) * VB + v] = val;
          s1[r] += val;
          s2[r] += val * val;
        }
      }
    }
  }
#pragma unroll
  for (int off = 1; off < 16; off <<= 1) {
#pragma unroll
    for (int r = 0; r < 4; ++r) {
      s1[r] += __shfl_xor(s1[r], off, 64);
      s2[r] += __shfl_xor(s2[r], off, 64);
    }
  }
  if (l15 == 0) {
#pragma unroll
    for (int r = 0; r < 4; ++r) { st1[orow + r] = s1[r]; st2[orow + r] = s2[r]; }
  }
  __syncthreads();
  if (tid < 96) {
    atomicAdd(&stats2[tid], st1[tid]);
    atomicAdd(&stats2[96 + tid], st2[tid]);
  }
}

// ---------------- K5: BN2 finalize (float4 elementwise) ----------------
__global__ __launch_bounds__(256) void k5_bn2(
    const float* __restrict__ out_pre, const float* __restrict__ stats2,
    const float* __restrict__ g2, const float* __restrict__ bt2,
    float* __restrict__ out) {
  int idx = blockIdx.x * 256 + threadIdx.x;
  if (idx >= NB * CB * TB * VB / 4) return;
  int o = (idx / (TB * VB / 4)) % CB;
  const float inv = 1.f / (8.f * 128.f * 25.f);
  float m = stats2[o] * inv;
  float var = stats2[96 + o] * inv - m * m;
  float a = g2[o] * rsqrtf(var + EPSB);
  float b = bt2[o] - m * a;
  f32x4 vin = reinterpret_cast<const f32x4*>(out_pre)[idx];
  f32x4 vo;
#pragma unroll
  for (int j = 0; j < 4; ++j) vo[j] = a * vin[j] + b;
  reinterpret_cast<f32x4*>(out)[idx] = vo;
}

extern "C" void kernel_launch(void* const* d_in, const int* in_sizes, int n_in,
                              void* d_out, int out_size, void* d_ws, size_t ws_size,
                              hipStream_t stream) {
  const float* x   = (const float*)d_in[0];
  const float* As  = (const float*)d_in[1];
  const float* Bs  = (const float*)d_in[2];
  const float* Ar  = (const float*)d_in[3];
  const float* Wm  = (const float*)d_in[4];
  const float* bm  = (const float*)d_in[5];
  const float* g1  = (const float*)d_in[6];
  const float* bt1 = (const float*)d_in[7];
  const float* Wo  = (const float*)d_in[8];
  const float* bo  = (const float*)d_in[9];
  const float* g2  = (const float*)d_in[10];
  const float* bt2 = (const float*)d_in[11];
  float* out = (float*)d_out;

  char* base = (char*)d_ws;
  unsigned short* HR   = (unsigned short*)base;                  // 14,745,600 B
  float* out_pre       = (float*)(base + 14745600);              //  9,830,400 B
  unsigned short* ABbf = (unsigned short*)(base + 24576000);     //    184,320 B
  unsigned short* Wbf  = (unsigned short*)(base + 24760320);     //    221,184 B
  unsigned short* Wobf = (unsigned short*)(base + 24981504);     //     55,296 B
  float* stats         = (float*)(base + 25036800);              //      1,536 B
  float* stats1 = stats, *stats2 = stats + 192;

  k0_init<<<432, 256, 0, stream>>>(As, Bs, Ar, Wm, Wo, ABbf, Wbf, Wobf, stats);
  k1t2<<<NB * TB / 2, 384, 0, stream>>>(x, ABbf, Wbf, bm, HR, stats1);
  k3n<<<NB * TB / 2, 384, 0, stream>>>(HR, stats1, g1, bt1, Wobf, bo, out_pre, stats2);
  k5_bn2<<<(NB * CB * TB * VB / 4 + 255) / 256, 256, 0, stream>>>(out_pre, stats2, g2, bt2, out);
}

// Round 7
// 189.978 us; speedup vs baseline: 1.3962x; 1.3021x over previous
//
#include <hip/hip_runtime.h>

// MS-G3D block. bf16-MFMA, t-chunk=2 fused k1 with fragment-swizzled weights:
// every global load in the hot loop is a coalesced dwordx4 (base + lane*16B).
// N=8, C=96, T=128, V=25, WIN=3, VL=75, NS=6.

#define NB 8
#define CB 96
#define TB 128
#define VB 25
#define VLB 75
#define EPSB 1e-5f
#define XRS 104   // xraw row stride (shorts)
#define TMS 104   // tmp row stride
#define HBS 296   // hnb row stride (shorts)

typedef __attribute__((ext_vector_type(8))) short bf16x8;
typedef __attribute__((ext_vector_type(4))) float f32x4;

__device__ inline unsigned short f2bf(float f) {
  unsigned int u = __float_as_uint(f);
  u = (u + 0x7FFFu + ((u >> 16) & 1u)) >> 16;
  return (unsigned short)u;
}
__device__ inline float bf2f(unsigned short u) {
  return __uint_as_float(((unsigned int)u) << 16);
}

// ---------------- K0: build fragment-swizzled bf16 weights; zero stats -------
// Wsw  [ps][wave][kk][lane][j] : W_ps[o=wave*16+(lane&15)][c=kk*32+(lane>>4)*8+j]
// ABsw [ps][nt][kk][lane][j]   : AB_ps[u=nt*16+(lane&15)][u'=kk*32+(lane>>4)*8+j]
// Wosw [wave][kk][lane][j]     : Wo[o=wave*16+(lane&15)][k=kk*32+(lane>>4)*8+j]
__global__ __launch_bounds__(256) void k0_init(
    const float* __restrict__ As, const float* __restrict__ Bs,
    const float* __restrict__ Ar, const float* __restrict__ Wm,
    const float* __restrict__ Wo,
    unsigned short* __restrict__ ABsw, unsigned short* __restrict__ Wsw,
    unsigned short* __restrict__ Wosw, float* __restrict__ stats) {
  int i = blockIdx.x * 256 + threadIdx.x;
  if (i < 110592) {                     // Wsw: 12*6*3*512
    int ps = i / 9216, r = i % 9216;
    int wv = r / 1536, r2 = r % 1536;
    int kk = r2 / 512, r3 = r2 % 512;
    int lane = r3 / 8, j = r3 % 8;
    int o = wv * 16 + (lane & 15);
    int c = kk * 32 + (lane >> 4) * 8 + j;
    Wsw[i] = f2bf(Wm[o * 1152 + ps * 96 + c]);
  }
  if (i < 92160) {                      // ABsw: 12*5*3*512
    int ps = i / 7680, r = i % 7680;
    int nt = r / 1536, r2 = r % 1536;
    int kk = r2 / 512, r3 = r2 % 512;
    int lane = r3 / 8, j = r3 % 8;
    int u = nt * 16 + (lane & 15);
    int up = kk * 32 + (lane >> 4) * 8 + j;
    float v = 0.f;
    if (u < 75 && up < 75) {
      int path = ps / 6, s = ps % 6;
      int idx = (s * 75 + u) * 75 + up;
      v = (path == 0 ? As[idx] : Bs[idx]) + Ar[idx];
    }
    ABsw[i] = f2bf(v);
  }
  if (i < 27648) {                      // Wosw: 6*9*512
    int wv = i / 4608, r = i % 4608;
    int kk = r / 512, r3 = r % 512;
    int lane = r3 / 8, j = r3 % 8;
    int o = wv * 16 + (lane & 15);
    int k = kk * 32 + (lane >> 4) * 8 + j;
    Wosw[i] = f2bf(Wo[o * 288 + k]);
  }
  if (i < 384) stats[i] = 0.f;
}

// ---------------- K1: t2 fused (MLP -> agg) x12 MFMA, swizzled weights -------
// grid = N*T/2 = 512 blocks, 384 threads (6 waves). Wave w owns o-rows [16w,16w+16).
__global__ __launch_bounds__(384, 2) void k1t2(
    const float* __restrict__ x, const unsigned short* __restrict__ ABsw,
    const unsigned short* __restrict__ Wsw, const float* __restrict__ bm,
    unsigned short* __restrict__ h_relu, float* __restrict__ stats1) {
  __shared__ unsigned short xraw[112 * XRS];     // rows r=tt_rel*25+v, 100..111 zero
  __shared__ unsigned short tmp_s[2][96 * TMS];  // per-dt tmp [o][u']
  __shared__ float st1s[96], st2s[96];
  const int tid = threadIdx.x;
  const int n = blockIdx.x >> 6, t0 = (blockIdx.x & 63) * 2;
  const int wave = tid >> 6, lane = tid & 63;
  const int l15 = lane & 15, quad = lane >> 4, q8 = quad * 8;
  const int wrow16 = wave * 16;

  // stage raw x slice: tt = t0-1 .. t0+2 (100 rows), zero-pad rows to 112
  for (int idx = tid; idx < 96 * 112; idx += 384) {
    int c = idx / 112, r = idx - c * 112;
    float v = 0.f;
    if (r < 100) {
      int tt = t0 - 1 + r / 25, vv = r % 25;
      if (tt >= 0 && tt < TB) v = x[((n * CB + c) * TB + tt) * VB + vv];
    }
    xraw[r * XRS + c] = f2bf(v);
  }
  // zero tmp K-pad cols [80,96) for both buffers (cols 75..79 written 0 each ps)
  for (int idx = tid; idx < 2 * 96 * 16; idx += 384) {
    int b = idx / (96 * 16), rem = idx - b * 96 * 16;
    tmp_s[b][(rem / 16) * TMS + 80 + rem % 16] = 0;
  }
  __syncthreads();

  const f32x4 zf = {0.f, 0.f, 0.f, 0.f};
  f32x4 acc2[2][5];
#pragma unroll
  for (int d = 0; d < 2; ++d)
#pragma unroll
    for (int nt = 0; nt < 5; ++nt) acc2[d][nt] = zf;

  const unsigned short* Wbase = Wsw + wave * 1536 + lane * 8;   // + ps*9216 + kk*512
  const unsigned short* Bbase = ABsw + lane * 8;                // + ps*7680 + (nt*3+kk)*512

#pragma unroll
  for (int ps = 0; ps < 12; ++ps) {
    // coalesced fragment loads (dwordx4, lane-contiguous)
    bf16x8 wa[3];
#pragma unroll
    for (int kk = 0; kk < 3; ++kk)
      wa[kk] = *reinterpret_cast<const bf16x8*>(Wbase + ps * 9216 + kk * 512);
    bf16x8 bf[15];
#pragma unroll
    for (int i = 0; i < 15; ++i)
      bf[i] = *reinterpret_cast<const bf16x8*>(Bbase + ps * 7680 + i * 512);

    // GEMM1 dt=0
    f32x4 acc1[5];
#pragma unroll
    for (int nt = 0; nt < 5; ++nt) acc1[nt] = zf;
#pragma unroll
    for (int kk = 0; kk < 3; ++kk)
#pragma unroll
      for (int nt = 0; nt < 5; ++nt) {
        bf16x8 b = *reinterpret_cast<const bf16x8*>(&xraw[(nt * 16 + l15) * XRS + kk * 32 + q8]);
        acc1[nt] = __builtin_amdgcn_mfma_f32_16x16x32_bf16(wa[kk], b, acc1[nt], 0, 0, 0);
      }
#pragma unroll
    for (int nt = 0; nt < 5; ++nt) {
      int col = nt * 16 + l15;
#pragma unroll
      for (int r = 0; r < 4; ++r) {
        unsigned short v = (col < 75) ? f2bf(acc1[nt][r]) : (unsigned short)0;
        tmp_s[0][(wrow16 + quad * 4 + r) * TMS + col] = v;
      }
    }
    // GEMM1 dt=1 (covers tmp0 write->read latency)
#pragma unroll
    for (int nt = 0; nt < 5; ++nt) acc1[nt] = zf;
#pragma unroll
    for (int kk = 0; kk < 3; ++kk)
#pragma unroll
      for (int nt = 0; nt < 5; ++nt) {
        bf16x8 b = *reinterpret_cast<const bf16x8*>(&xraw[(25 + nt * 16 + l15) * XRS + kk * 32 + q8]);
        acc1[nt] = __builtin_amdgcn_mfma_f32_16x16x32_bf16(wa[kk], b, acc1[nt], 0, 0, 0);
      }
#pragma unroll
    for (int nt = 0; nt < 5; ++nt) {
      int col = nt * 16 + l15;
#pragma unroll
      for (int r = 0; r < 4; ++r) {
        unsigned short v = (col < 75) ? f2bf(acc1[nt][r]) : (unsigned short)0;
        tmp_s[1][(wrow16 + quad * 4 + r) * TMS + col] = v;
      }
    }

    // GEMM2 both dt; b-frags (registers) shared across dt
#pragma unroll
    for (int kk = 0; kk < 3; ++kk) {
      bf16x8 a0 = *reinterpret_cast<const bf16x8*>(&tmp_s[0][(wrow16 + l15) * TMS + kk * 32 + q8]);
#pragma unroll
      for (int nt = 0; nt < 5; ++nt)
        acc2[0][nt] = __builtin_amdgcn_mfma_f32_16x16x32_bf16(a0, bf[nt * 3 + kk], acc2[0][nt], 0, 0, 0);
      bf16x8 a1 = *reinterpret_cast<const bf16x8*>(&tmp_s[1][(wrow16 + l15) * TMS + kk * 32 + q8]);
#pragma unroll
      for (int nt = 0; nt < 5; ++nt)
        acc2[1][nt] = __builtin_amdgcn_mfma_f32_16x16x32_bf16(a1, bf[nt * 3 + kk], acc2[1][nt], 0, 0, 0);
    }
  }

  // epilogue: bias + relu + bf16 store + BN1 partial stats (both dt)
  const int orow = wrow16 + quad * 4;
  float s1[4] = {0.f, 0.f, 0.f, 0.f}, s2[4] = {0.f, 0.f, 0.f, 0.f};
#pragma unroll
  for (int d = 0; d < 2; ++d) {
    const int t = t0 + d;
#pragma unroll
    for (int r = 0; r < 4; ++r) {
      const int o = orow + r;
      const float bias = bm[o];
      unsigned short* hp = h_relu + ((n * CB + o) * TB + t) * VLB;
#pragma unroll
      for (int nt = 0; nt < 5; ++nt) {
        int u = nt * 16 + l15;
        if (u < VLB) {
          float v = acc2[d][nt][r] + bias;
          v = v > 0.f ? v : 0.f;
          hp[u] = f2bf(v);
          s1[r] += v;
          s2[r] += v * v;
        }
      }
    }
  }
#pragma unroll
  for (int off = 1; off < 16; off <<= 1) {
#pragma unroll
    for (int r = 0; r < 4; ++r) {
      s1[r] += __shfl_xor(s1[r], off, 64);
      s2[r] += __shfl_xor(s2[r], off, 64);
    }
  }
  if (l15 == 0) {
#pragma unroll
    for (int r = 0; r < 4; ++r) { st1s[orow + r] = s1[r]; st2s[orow + r] = s2[r]; }
  }
  __syncthreads();
  if (tid < 96) {
    atomicAdd(&stats1[tid], st1s[tid]);
    atomicAdd(&stats1[96 + tid], st2s[tid]);
  }
}

// ---------------- K3: BN1-finalize + relu + out_conv (MFMA, 2 t/blk) --------
__global__ __launch_bounds__(384) void k3n(
    const unsigned short* __restrict__ h_relu, const float* __restrict__ stats1,
    const float* __restrict__ g1, const float* __restrict__ bt1,
    const unsigned short* __restrict__ Wosw, const float* __restrict__ bo,
    float* __restrict__ out_pre, float* __restrict__ stats2) {
  __shared__ unsigned short hnb[2][32 * HBS];
  __shared__ float a1s[96], b1s[96];
  __shared__ float st1[96], st2[96];
  const int tid = threadIdx.x;
  const int n = blockIdx.x >> 6, t0 = (blockIdx.x & 63) * 2;

  if (tid < 96) {
    const float inv = 1.f / (8.f * 128.f * 75.f);
    float m = stats1[tid] * inv;
    float var = stats1[96 + tid] * inv - m * m;
    float a = g1[tid] * rsqrtf(var + EPSB);
    a1s[tid] = a;
    b1s[tid] = bt1[tid] - m * a;
  }
  for (int idx = tid; idx < 2 * 7 * HBS; idx += 384) {
    int d = idx / (7 * HBS), rm = idx % (7 * HBS);
    hnb[d][25 * HBS + rm] = 0;
  }
  __syncthreads();

  for (int idx = tid; idx < 2 * 96 * 75; idx += 384) {
    int d = idx / 7200, rm = idx % 7200;
    int i = rm / 75, u = rm - i * 75;
    float hv = bf2f(h_relu[((n * CB + i) * TB + t0 + d) * VLB + u]);
    float v = a1s[i] * hv + b1s[i];
    v = v > 0.f ? v : 0.f;
    int w = u / 25, vv = u - w * 25;
    hnb[d][vv * HBS + i * 3 + w] = f2bf(v);
  }
  __syncthreads();

  const int wave = tid >> 6, lane = tid & 63;
  const int l15 = lane & 15, quad = lane >> 4, q8 = quad * 8;
  const f32x4 zf = {0.f, 0.f, 0.f, 0.f};
  f32x4 acc[2][2] = {{zf, zf}, {zf, zf}};
  const unsigned short* Apw = Wosw + wave * 4608 + lane * 8;
#pragma unroll
  for (int kk = 0; kk < 9; ++kk) {
    bf16x8 a = *reinterpret_cast<const bf16x8*>(Apw + kk * 512);
#pragma unroll
    for (int d = 0; d < 2; ++d) {
      bf16x8 b0 = *reinterpret_cast<const bf16x8*>(&hnb[d][l15 * HBS + kk * 32 + q8]);
      bf16x8 b1 = *reinterpret_cast<const bf16x8*>(&hnb[d][(16 + l15) * HBS + kk * 32 + q8]);
      acc[d][0] = __builtin_amdgcn_mfma_f32_16x16x32_bf16(a, b0, acc[d][0], 0, 0, 0);
      acc[d][1] = __builtin_amdgcn_mfma_f32_16x16x32_bf16(a, b1, acc[d][1], 0, 0, 0);
    }
  }

  const int orow = wave * 16 + quad * 4;
  float s1[4] = {0.f, 0.f, 0.f, 0.f}, s2[4] = {0.f, 0.f, 0.f, 0.f};
#pragma unroll
  for (int d = 0; d < 2; ++d) {
#pragma unroll
    for (int nt = 0; nt < 2; ++nt) {
      int v = nt * 16 + l15;
      if (v < VB) {
#pragma unroll
        for (int r = 0; r < 4; ++r) {
          const int o = orow + r;
          float val = acc[d][nt][r] + bo[o];
          out_pre[((n * CB + o) * TB + t0 + d) * VB + v] = val;
          s1[r] += val;
          s2[r] += val * val;
        }
      }
    }
  }
#pragma unroll
  for (int off = 1; off < 16; off <<= 1) {
#pragma unroll
    for (int r = 0; r < 4; ++r) {
      s1[r] += __shfl_xor(s1[r], off, 64);
      s2[r] += __shfl_xor(s2[r], off, 64);
    }
  }
  if (l15 == 0) {
#pragma unroll
    for (int r = 0; r < 4; ++r) { st1[orow + r] = s1[r]; st2[orow + r] = s2[r]; }
  }
  __syncthreads();
  if (tid < 96) {
    atomicAdd(&stats2[tid], st1[tid]);
    atomicAdd(&stats2[96 + tid], st2[tid]);
  }
}

// ---------------- K5: BN2 finalize (float4 elementwise) ----------------
__global__ __launch_bounds__(256) void k5_bn2(
    const float* __restrict__ out_pre, const float* __restrict__ stats2,
    const float* __restrict__ g2, const float* __restrict__ bt2,
    float* __restrict__ out) {
  int idx = blockIdx.x * 256 + threadIdx.x;
  if (idx >= NB * CB * TB * VB / 4) return;
  int o = (idx / (TB * VB / 4)) % CB;
  const float inv = 1.f / (8.f * 128.f * 25.f);
  float m = stats2[o] * inv;
  float var = stats2[96 + o] * inv - m * m;
  float a = g2[o] * rsqrtf(var + EPSB);
  float b = bt2[o] - m * a;
  f32x4 vin = reinterpret_cast<const f32x4*>(out_pre)[idx];
  f32x4 vo;
#pragma unroll
  for (int j = 0; j < 4; ++j) vo[j] = a * vin[j] + b;
  reinterpret_cast<f32x4*>(out)[idx] = vo;
}

extern "C" void kernel_launch(void* const* d_in, const int* in_sizes, int n_in,
                              void* d_out, int out_size, void* d_ws, size_t ws_size,
                              hipStream_t stream) {
  const float* x   = (const float*)d_in[0];
  const float* As  = (const float*)d_in[1];
  const float* Bs  = (const float*)d_in[2];
  const float* Ar  = (const float*)d_in[3];
  const float* Wm  = (const float*)d_in[4];
  const float* bm  = (const float*)d_in[5];
  const float* g1  = (const float*)d_in[6];
  const float* bt1 = (const float*)d_in[7];
  const float* Wo  = (const float*)d_in[8];
  const float* bo  = (const float*)d_in[9];
  const float* g2  = (const float*)d_in[10];
  const float* bt2 = (const float*)d_in[11];
  float* out = (float*)d_out;

  char* base = (char*)d_ws;
  unsigned short* HR   = (unsigned short*)base;                  // 14,745,600 B
  float* out_pre       = (float*)(base + 14745600);              //  9,830,400 B
  unsigned short* ABsw = (unsigned short*)(base + 24576000);     //    184,320 B
  unsigned short* Wsw  = (unsigned short*)(base + 24760320);     //    221,184 B
  unsigned short* Wosw = (unsigned short*)(base + 24981504);     //     55,296 B
  float* stats         = (float*)(base + 25036800);              //      1,536 B
  float* stats1 = stats, *stats2 = stats + 192;

  k0_init<<<432, 256, 0, stream>>>(As, Bs, Ar, Wm, Wo, ABsw, Wsw, Wosw, stats);
  k1t2<<<NB * TB / 2, 384, 0, stream>>>(x, ABsw, Wsw, bm, HR, stats1);
  k3n<<<NB * TB / 2, 384, 0, stream>>>(HR, stats1, g1, bt1, Wosw, bo, out_pre, stats2);
  k5_bn2<<<(NB * CB * TB * VB / 4 + 255) / 256, 256, 0, stream>>>(out_pre, stats2, g2, bt2, out);
}